// Round 1
// baseline (454.707 us; speedup 1.0000x reference)
//
#include <hip/hip_runtime.h>
#include <math.h>

// FocalLoss: pred, target fp32 [B=8, C=21, H=512, W=512]
// ce[b,c] = mean_h( -sum_w target * log_softmax(pred, axis=w) )
// out = mean_b( sum_c( ALPHA*(1-exp(-ce))^2 * ce ) )

#define B_DIM 8
#define C_DIM 21
#define H_DIM 512
#define W_DIM 512
#define N_ROWS (B_DIM * C_DIM * H_DIM)   // 86016
#define N_BC   (B_DIM * C_DIM)           // 168
#define ALPHA_F 0.25f

// One wave (64 lanes) per row of 512; 4 waves per 256-thread block.
__global__ __launch_bounds__(256) void focal_rows(
    const float* __restrict__ pred,
    const float* __restrict__ target,
    float* __restrict__ acc /* N_BC floats, pre-zeroed */) {

    const int wave = threadIdx.x >> 6;
    const int lane = threadIdx.x & 63;
    const int row  = blockIdx.x * 4 + wave;   // grid sized exactly: no guard needed
    const long long base = (long long)row * W_DIM + lane * 8;

    const float4 p0 = *reinterpret_cast<const float4*>(pred + base);
    const float4 p1 = *reinterpret_cast<const float4*>(pred + base + 4);
    const float4 t0 = *reinterpret_cast<const float4*>(target + base);
    const float4 t1 = *reinterpret_cast<const float4*>(target + base + 4);

    // ---- wave max of pred ----
    float m = fmaxf(fmaxf(fmaxf(p0.x, p0.y), fmaxf(p0.z, p0.w)),
                    fmaxf(fmaxf(p1.x, p1.y), fmaxf(p1.z, p1.w)));
#pragma unroll
    for (int off = 32; off > 0; off >>= 1)
        m = fmaxf(m, __shfl_xor(m, off, 64));

    // ---- per-lane partials ----
    float se = __expf(p0.x - m) + __expf(p0.y - m) + __expf(p0.z - m) + __expf(p0.w - m)
             + __expf(p1.x - m) + __expf(p1.y - m) + __expf(p1.z - m) + __expf(p1.w - m);
    float st = (t0.x + t0.y) + (t0.z + t0.w) + (t1.x + t1.y) + (t1.z + t1.w);
    float stp = t0.x * p0.x + t0.y * p0.y + t0.z * p0.z + t0.w * p0.w
              + t1.x * p1.x + t1.y * p1.y + t1.z * p1.z + t1.w * p1.w;

#pragma unroll
    for (int off = 32; off > 0; off >>= 1) {
        se  += __shfl_xor(se,  off, 64);
        st  += __shfl_xor(st,  off, 64);
        stp += __shfl_xor(stp, off, 64);
    }

    if (lane == 0) {
        // -sum_w t*(p - m - log(se)) = (m + log(se))*sum(t) - sum(t*p)
        const float ce_row = (m + logf(se)) * st - stp;
        atomicAdd(&acc[row >> 9], ce_row);   // row/H_DIM -> (b,c) index
    }
}

__global__ __launch_bounds__(256) void focal_finalize(
    const float* __restrict__ acc, float* __restrict__ out) {

    const int t = threadIdx.x;
    float f = 0.0f;
    if (t < N_BC) {
        const float ce = acc[t] * (1.0f / (float)H_DIM);
        const float pt = __expf(-ce);
        const float omp = 1.0f - pt;
        f = ALPHA_F * omp * omp * ce;
    }
#pragma unroll
    for (int off = 32; off > 0; off >>= 1)
        f += __shfl_xor(f, off, 64);

    __shared__ float ws[4];
    if ((t & 63) == 0) ws[t >> 6] = f;
    __syncthreads();
    if (t == 0)
        out[0] = (ws[0] + ws[1] + ws[2] + ws[3]) * (1.0f / (float)B_DIM);
}

extern "C" void kernel_launch(void* const* d_in, const int* in_sizes, int n_in,
                              void* d_out, int out_size, void* d_ws, size_t ws_size,
                              hipStream_t stream) {
    const float* pred   = (const float*)d_in[0];
    const float* target = (const float*)d_in[1];
    float* out = (float*)d_out;
    float* acc = (float*)d_ws;

    hipMemsetAsync(acc, 0, N_BC * sizeof(float), stream);
    focal_rows<<<N_ROWS / 4, 256, 0, stream>>>(pred, target, acc);
    focal_finalize<<<1, 256, 0, stream>>>(acc, out);
}

// Round 2
// 64.925 us; speedup vs baseline: 7.0036x; 7.0036x over previous
//
#include <hip/hip_runtime.h>
#include <math.h>

// FocalLoss: pred, target fp32 [B=8, C=21, H=512, W=512]
// ce[b,c] = mean_h( -sum_w target * log_softmax(pred, axis=w) )
// out = mean_b( sum_c( ALPHA*(1-exp(-ce))^2 * ce ) )

#define B_DIM 8
#define C_DIM 21
#define H_DIM 512
#define W_DIM 512
#define N_ROWS (B_DIM * C_DIM * H_DIM)   // 86016
#define N_BC   (B_DIM * C_DIM)           // 168
#define ALPHA_F 0.25f

// Stage 1: one wave (64 lanes) per row of 512; 4 waves per 256-thread block.
// Plain store of per-row CE -- NO atomics (prior version serialized on 168
// contended atomic addresses: 446us for a 56us-floor kernel).
__global__ __launch_bounds__(256) void focal_rows(
    const float* __restrict__ pred,
    const float* __restrict__ target,
    float* __restrict__ row_ce /* N_ROWS floats */) {

    const int wave = threadIdx.x >> 6;
    const int lane = threadIdx.x & 63;
    const int row  = blockIdx.x * 4 + wave;   // grid sized exactly
    const long long base = (long long)row * W_DIM + lane * 8;

    const float4 p0 = *reinterpret_cast<const float4*>(pred + base);
    const float4 p1 = *reinterpret_cast<const float4*>(pred + base + 4);
    const float4 t0 = *reinterpret_cast<const float4*>(target + base);
    const float4 t1 = *reinterpret_cast<const float4*>(target + base + 4);

    // ---- wave max of pred ----
    float m = fmaxf(fmaxf(fmaxf(p0.x, p0.y), fmaxf(p0.z, p0.w)),
                    fmaxf(fmaxf(p1.x, p1.y), fmaxf(p1.z, p1.w)));
#pragma unroll
    for (int off = 32; off > 0; off >>= 1)
        m = fmaxf(m, __shfl_xor(m, off, 64));

    // ---- per-lane partials ----
    float se = __expf(p0.x - m) + __expf(p0.y - m) + __expf(p0.z - m) + __expf(p0.w - m)
             + __expf(p1.x - m) + __expf(p1.y - m) + __expf(p1.z - m) + __expf(p1.w - m);
    float st = (t0.x + t0.y) + (t0.z + t0.w) + (t1.x + t1.y) + (t1.z + t1.w);
    float stp = t0.x * p0.x + t0.y * p0.y + t0.z * p0.z + t0.w * p0.w
              + t1.x * p1.x + t1.y * p1.y + t1.z * p1.z + t1.w * p1.w;

#pragma unroll
    for (int off = 32; off > 0; off >>= 1) {
        se  += __shfl_xor(se,  off, 64);
        st  += __shfl_xor(st,  off, 64);
        stp += __shfl_xor(stp, off, 64);
    }

    if (lane == 0) {
        // -sum_w t*(p - m - log(se)) = (m + log(se))*sum(t) - sum(t*p)
        row_ce[row] = (m + logf(se)) * st - stp;
    }
}

// Stage 2: one wave per (b,c): reduce 512 row CEs, apply focal transform.
__global__ __launch_bounds__(64) void focal_bc(
    const float* __restrict__ row_ce, float* __restrict__ focal /* N_BC */) {

    const int bc   = blockIdx.x;
    const int lane = threadIdx.x;
    const float4 a = *reinterpret_cast<const float4*>(row_ce + bc * H_DIM + lane * 8);
    const float4 b = *reinterpret_cast<const float4*>(row_ce + bc * H_DIM + lane * 8 + 4);
    float s = (a.x + a.y) + (a.z + a.w) + (b.x + b.y) + (b.z + b.w);
#pragma unroll
    for (int off = 32; off > 0; off >>= 1)
        s += __shfl_xor(s, off, 64);

    if (lane == 0) {
        const float ce = s * (1.0f / (float)H_DIM);
        const float pt = __expf(-ce);
        const float omp = 1.0f - pt;
        focal[bc] = ALPHA_F * omp * omp * ce;
    }
}

// Stage 3: one wave, deterministic sum of 168 focals -> scalar.
__global__ __launch_bounds__(64) void focal_final(
    const float* __restrict__ focal, float* __restrict__ out) {

    const int lane = threadIdx.x;
    float f = 0.0f;
#pragma unroll
    for (int i = 0; i < 3; ++i) {
        const int idx = lane + i * 64;
        if (idx < N_BC) f += focal[idx];
    }
#pragma unroll
    for (int off = 32; off > 0; off >>= 1)
        f += __shfl_xor(f, off, 64);
    if (lane == 0)
        out[0] = f * (1.0f / (float)B_DIM);
}

extern "C" void kernel_launch(void* const* d_in, const int* in_sizes, int n_in,
                              void* d_out, int out_size, void* d_ws, size_t ws_size,
                              hipStream_t stream) {
    const float* pred   = (const float*)d_in[0];
    const float* target = (const float*)d_in[1];
    float* out = (float*)d_out;

    float* row_ce = (float*)d_ws;                  // 86016 floats = 344 KB
    float* focal  = (float*)d_ws + N_ROWS;         // 168 floats

    focal_rows<<<N_ROWS / 4, 256, 0, stream>>>(pred, target, row_ce);
    focal_bc<<<N_BC, 64, 0, stream>>>(row_ce, focal);
    focal_final<<<1, 64, 0, stream>>>(focal, out);
}